// Round 6
// baseline (27.946 us; speedup 1.0000x reference)
//
#include <hip/hip_runtime.h>
#include <hip/hip_bf16.h>
#include <math.h>

typedef __attribute__((ext_vector_type(8))) short short8;
typedef __attribute__((ext_vector_type(4))) float f32x4;

#define LOG2E 1.44269504088896340736f

__device__ __forceinline__ short bf16bits(float x) {
    __hip_bfloat16 b = __float2bfloat16(x);
    short r;
    __builtin_memcpy(&r, &b, 2);
    return r;
}

__device__ __forceinline__ short8 cvt8(const float4 u, const float4 v) {
    short8 r;
    r[0] = bf16bits(u.x); r[1] = bf16bits(u.y); r[2] = bf16bits(u.z); r[3] = bf16bits(u.w);
    r[4] = bf16bits(v.x); r[5] = bf16bits(v.y); r[6] = bf16bits(v.z); r[7] = bf16bits(v.w);
    return r;
}

__device__ __forceinline__ float sq8(const float4 u, const float4 v) {
    return u.x*u.x + u.y*u.y + u.z*u.z + u.w*u.w
         + v.x*v.x + v.y*v.y + v.z*v.z + v.w*v.w;
}

// ---------------- main: fused convert + MFMA cross + exp-sum, partial out ---
// Grid (n_test/16 rowgroups, 8 col-chunks of 512) = 1024 blocks x 512 thr
// (8 waves). Wave wv covers cols [cc*512 + wv*64, +64) in 4 steps of 16.
// All conversion f32->bf16 and norm computation done in-register (no prep
// kernel): A/B fragments loaded as float4s straight from the f32 inputs
// (L2-resident), converted with cvt8; row/col sq-norms via 2 shfl_xor over
// the kg bits. K=64 via 2 chained mfma_f32_16x16x32_bf16; A lane(l&15)=row,
// k-chunk (l>>4)*8; B identical packing (consistent k-bijection preserves
// the dot). C/D layout (HW-verified m89): col=l&15, row=(l>>4)*4+reg.
// Block reduces 8 wave-partials via LDS, writes partial[cc][row].
// No atomics, no fences (round-2 lesson: device fences are catastrophic).
__global__ __launch_bounds__(512, 6) void kde_main(
    const float* __restrict__ testX, const float* __restrict__ trainX,
    const float* __restrict__ w, float* __restrict__ partial, int n_test)
{
    __shared__ float lds[16 * 8];   // [row][wave]

    const int mbase = blockIdx.x * 16;
    const int cc    = blockIdx.y;         // 0..7
    const int wv    = threadIdx.x >> 6;   // 0..7
    const int lane  = threadIdx.x & 63;
    const int cg    = lane & 15;          // col / A-row selector
    const int kg    = lane >> 4;          // k-chunk selector

    // ---- A: load f32 test row, convert in-register, norm via shuffles ----
    const int arow = mbase + cg;
    const float4 af0 = *(const float4*)(testX + arow * 64 + kg * 8);
    const float4 af1 = *(const float4*)(testX + arow * 64 + kg * 8 + 4);
    const float4 af2 = *(const float4*)(testX + arow * 64 + 32 + kg * 8);
    const float4 af3 = *(const float4*)(testX + arow * 64 + 32 + kg * 8 + 4);
    const short8 a0 = cvt8(af0, af1);
    const short8 a1 = cvt8(af2, af3);

    float sx = sq8(af0, af1) + sq8(af2, af3);
    sx += __shfl_xor(sx, 16);
    sx += __shfl_xor(sx, 32);             // full ||x_(mbase+cg)||^2 on all 4 kg lanes

    // sq-norm of the 4 test rows this lane's accumulator covers (C rows).
    float sxr[4];
    #pragma unroll
    for (int r = 0; r < 4; ++r) sxr[r] = __shfl(sx, kg * 4 + r);

    float s[4] = {0.f, 0.f, 0.f, 0.f};
    const int colbase = cc * 512 + wv * 64;

    #pragma unroll
    for (int step = 0; step < 4; ++step) {
        const int bcol = colbase + step * 16 + cg;
        const float4 bf0 = *(const float4*)(trainX + bcol * 64 + kg * 8);
        const float4 bf1 = *(const float4*)(trainX + bcol * 64 + kg * 8 + 4);
        const float4 bf2 = *(const float4*)(trainX + bcol * 64 + 32 + kg * 8);
        const float4 bf3 = *(const float4*)(trainX + bcol * 64 + 32 + kg * 8 + 4);
        const float ww  = w[bcol];
        const short8 b0 = cvt8(bf0, bf1);
        const short8 b1 = cvt8(bf2, bf3);

        float sy = sq8(bf0, bf1) + sq8(bf2, bf3);
        sy += __shfl_xor(sy, 16);
        sy += __shfl_xor(sy, 32);         // full ||y_bcol||^2
        const float nh = (-0.5f * LOG2E) * ww * ww;

        f32x4 acc = {0.f, 0.f, 0.f, 0.f};
        acc = __builtin_amdgcn_mfma_f32_16x16x32_bf16(a0, b0, acc, 0, 0, 0);
        acc = __builtin_amdgcn_mfma_f32_16x16x32_bf16(a1, b1, acc, 0, 0, 0);

        #pragma unroll
        for (int r = 0; r < 4; ++r) {
            float d2 = fmaxf(__builtin_fmaf(-2.0f, acc[r], sxr[r] + sy), 0.0f);
            s[r] += __builtin_exp2f(d2 * nh);
        }
    }

    // Reduce across the 16 col lanes (xor bits 0..3 keep kg fixed).
    #pragma unroll
    for (int m = 1; m < 16; m <<= 1) {
        #pragma unroll
        for (int r = 0; r < 4; ++r) s[r] += __shfl_xor(s[r], m);
    }
    if (cg == 0) {
        #pragma unroll
        for (int r = 0; r < 4; ++r)
            lds[(kg * 4 + r) * 8 + wv] = s[r];
    }
    __syncthreads();

    if (threadIdx.x < 16) {
        const int r = threadIdx.x;
        float sum = 0.f;
        #pragma unroll
        for (int v = 0; v < 8; ++v) sum += lds[r * 8 + v];
        partial[cc * n_test + mbase + r] = sum;
    }
}

// ---------------- final: combine col-chunk partials, log, -Z ----------------
__global__ __launch_bounds__(256) void kde_final(
    const float* __restrict__ partial, float* __restrict__ out,
    float Z, int n_test, int n_cc)
{
    const int i = blockIdx.x * 256 + threadIdx.x;
    if (i >= n_test) return;
    float sum = 0.f;
    for (int c = 0; c < n_cc; ++c) sum += partial[c * n_test + i];
    out[i] = __logf(sum) - Z;
}

extern "C" void kernel_launch(void* const* d_in, const int* in_sizes, int n_in,
                              void* d_out, int out_size, void* d_ws, size_t ws_size,
                              hipStream_t stream) {
    const float* testX  = (const float*)d_in[0];
    const float* trainX = (const float*)d_in[1];
    const float* w      = (const float*)d_in[2];
    float* out = (float*)d_out;

    const int d = 64;
    const int n_test  = in_sizes[0] / d;   // 2048
    const int n_train = in_sizes[1] / d;   // 4096
    const int n_cc    = 8;                 // col-chunks of n_train/8 = 512

    float* partial = (float*)d_ws;         // [n_cc][n_test]
    (void)ws_size; (void)n_in; (void)out_size;

    const float Z = 0.5f * d * logf(2.0f * (float)M_PI) + logf((float)n_train);

    dim3 grid(n_test / 16, n_cc);
    kde_main<<<grid, 512, 0, stream>>>(testX, trainX, w, partial, n_test);

    kde_final<<<(n_test + 255) / 256, 256, 0, stream>>>(
        partial, out, Z, n_test, n_cc);
}

// Round 7
// 25.838 us; speedup vs baseline: 1.0816x; 1.0816x over previous
//
#include <hip/hip_runtime.h>
#include <hip/hip_bf16.h>
#include <math.h>

typedef __attribute__((ext_vector_type(8))) short short8;
typedef __attribute__((ext_vector_type(4))) short short4v;
typedef __attribute__((ext_vector_type(4))) float f32x4;

#define LOG2E 1.44269504088896340736f

__device__ __forceinline__ short bf16bits(float x) {
    __hip_bfloat16 b = __float2bfloat16(x);
    short r;
    __builtin_memcpy(&r, &b, 2);
    return r;
}

// ---------------- prep: f32 -> bf16 rows, row sq-norms, packed col params ----
// One wave handles 4 rows: lane = sub(2b)*16 + q(4b); row = wid*4+sub,
// dims q*4..q*4+3 via float4 load, short4 bf16 store. 16-lane shfl reduce
// for the sq-norm. Train rows also emit snh[j] = {||y||^2, -0.5*log2e*w^2}.
__global__ __launch_bounds__(256) void kde_prep(
    const float* __restrict__ testX, const float* __restrict__ trainX,
    const float* __restrict__ w,
    __hip_bfloat16* __restrict__ testbf, __hip_bfloat16* __restrict__ trainbf,
    float* __restrict__ sqx, float2* __restrict__ snh,
    int n_test, int n_train)
{
    const int tid  = threadIdx.x;
    const int wid  = blockIdx.x * 4 + (tid >> 6);
    const int lane = tid & 63;
    const int sub  = lane >> 4;
    const int q    = lane & 15;
    const int row  = wid * 4 + sub;
    if (row >= n_test + n_train) return;

    const float* src;
    __hip_bfloat16* dst;
    int r_local;
    if (row < n_test) { src = testX;  dst = testbf;  r_local = row; }
    else              { src = trainX; dst = trainbf; r_local = row - n_test; }

    const float4 v = ((const float4*)src)[r_local * 16 + q];
    short4v b = { bf16bits(v.x), bf16bits(v.y), bf16bits(v.z), bf16bits(v.w) };
    *(short4v*)(dst + r_local * 64 + q * 4) = b;

    float s = v.x * v.x + v.y * v.y + v.z * v.z + v.w * v.w;
    #pragma unroll
    for (int m = 1; m < 16; m <<= 1) s += __shfl_xor(s, m);
    if (q == 0) {
        if (row < n_test) sqx[r_local] = s;
        else {
            float ww = w[r_local];
            snh[r_local] = make_float2(s, -0.5f * LOG2E * ww * ww);
        }
    }
}

// ---------------- main: MFMA cross + fused exp-sum, wave-private partials ---
// Grid (n_test/16 = 128, n_train/256 = 16) = 2048 blocks x 256 thr (4 waves)
// -> 8 blocks/CU x 4 waves = 32 waves/CU, full occupancy, single dispatch
// round. Wave wv covers cols [blockIdx.y*256 + wv*64, +64) in 4 steps of 16.
// K=64 via 2 chained mfma_f32_16x16x32_bf16, fragments straight from global
// (L2-resident). A: lane(l&15)=test row, k-chunk (l>>4)*8; B: identical
// packing (consistent k-bijection preserves the dot). C/D layout (HW-verified
// m89): col=l&15, row=(l>>4)*4+reg.
// NO LDS, NO barriers, NO atomics: after the 16-lane shfl reduce, lanes
// cg==0 (kg=0..3) write their 4 row-partials as one float4 to the wave's
// private slot partial[slot][mbase+kg*4]. 64 slots per row, summed by final.
__global__ __launch_bounds__(256, 8) void kde_main(
    const __hip_bfloat16* __restrict__ testbf,
    const __hip_bfloat16* __restrict__ trainbf,
    const float* __restrict__ sqx, const float2* __restrict__ snh,
    float* __restrict__ partial, int n_test)
{
    const int mbase = blockIdx.x * 16;
    const int wv    = threadIdx.x >> 6;   // 0..3
    const int lane  = threadIdx.x & 63;
    const int cg    = lane & 15;          // col / A-row selector
    const int kg    = lane >> 4;          // k-chunk selector

    // A fragments: test rows, hoisted out of the col loop.
    const int arow = mbase + cg;
    const short8 a0 = *(const short8*)(testbf + arow * 64 +      kg * 8);
    const short8 a1 = *(const short8*)(testbf + arow * 64 + 32 + kg * 8);

    // sq-norm of the 4 test rows this lane's accumulator covers.
    float sxr[4];
    #pragma unroll
    for (int r = 0; r < 4; ++r) sxr[r] = sqx[mbase + kg * 4 + r];

    float s[4] = {0.f, 0.f, 0.f, 0.f};
    const int colbase = blockIdx.y * 256 + wv * 64;

    #pragma unroll
    for (int step = 0; step < 4; ++step) {
        const int bcol = colbase + step * 16 + cg;
        const short8 b0 = *(const short8*)(trainbf + bcol * 64 +      kg * 8);
        const short8 b1 = *(const short8*)(trainbf + bcol * 64 + 32 + kg * 8);
        const float2 p  = snh[bcol];      // {||y||^2, -0.5*log2e*w^2}

        f32x4 acc = {0.f, 0.f, 0.f, 0.f};
        acc = __builtin_amdgcn_mfma_f32_16x16x32_bf16(a0, b0, acc, 0, 0, 0);
        acc = __builtin_amdgcn_mfma_f32_16x16x32_bf16(a1, b1, acc, 0, 0, 0);

        #pragma unroll
        for (int r = 0; r < 4; ++r) {
            float d2 = fmaxf(__builtin_fmaf(-2.0f, acc[r], sxr[r] + p.x), 0.0f);
            s[r] += __builtin_exp2f(d2 * p.y);
        }
    }

    // Reduce across the 16 col lanes (xor bits 0..3 keep kg fixed).
    #pragma unroll
    for (int m = 1; m < 16; m <<= 1) {
        #pragma unroll
        for (int r = 0; r < 4; ++r) s[r] += __shfl_xor(s[r], m);
    }

    // Wave-private partial write: no LDS, no barrier, no atomics.
    if (cg == 0) {
        const int slot = blockIdx.y * 4 + wv;          // 0..63
        float4 v4 = make_float4(s[0], s[1], s[2], s[3]);
        *(float4*)(partial + (size_t)slot * n_test + mbase + kg * 4) = v4;
    }
}

// ---------------- final: combine wave-slot partials, log, -Z ----------------
__global__ __launch_bounds__(256) void kde_final(
    const float* __restrict__ partial, float* __restrict__ out,
    float Z, int n_test, int n_slots)
{
    const int i = blockIdx.x * 256 + threadIdx.x;
    if (i >= n_test) return;
    float sum = 0.f;
    #pragma unroll 8
    for (int c = 0; c < n_slots; ++c) sum += partial[(size_t)c * n_test + i];
    out[i] = __logf(sum) - Z;
}

extern "C" void kernel_launch(void* const* d_in, const int* in_sizes, int n_in,
                              void* d_out, int out_size, void* d_ws, size_t ws_size,
                              hipStream_t stream) {
    const float* testX  = (const float*)d_in[0];
    const float* trainX = (const float*)d_in[1];
    const float* w      = (const float*)d_in[2];
    float* out = (float*)d_out;

    const int d = 64;
    const int n_test  = in_sizes[0] / d;   // 2048
    const int n_train = in_sizes[1] / d;   // 4096
    const int n_slots = (n_train / 256) * 4;  // 64 wave-chunks of 64 cols

    char* ws = (char*)d_ws;
    size_t off = 0;
    __hip_bfloat16* testbf  = (__hip_bfloat16*)(ws + off); off += (size_t)n_test  * d * 2;
    __hip_bfloat16* trainbf = (__hip_bfloat16*)(ws + off); off += (size_t)n_train * d * 2;
    float*  sqx     = (float*)(ws + off);  off += (size_t)n_test * 4;
    float2* snh     = (float2*)(ws + off); off += (size_t)n_train * 8;
    float*  partial = (float*)(ws + off);  off += (size_t)n_slots * n_test * 4;
    (void)ws_size; (void)n_in; (void)out_size;

    const float Z = 0.5f * d * logf(2.0f * (float)M_PI) + logf((float)n_train);

    const int rows = n_test + n_train;                 // 6144
    kde_prep<<<rows / 16, 256, 0, stream>>>(
        testX, trainX, w, testbf, trainbf, sqx, snh, n_test, n_train);

    dim3 grid(n_test / 16, n_train / 256);
    kde_main<<<grid, 256, 0, stream>>>(
        testbf, trainbf, sqx, snh, partial, n_test);

    kde_final<<<(n_test + 255) / 256, 256, 0, stream>>>(
        partial, out, Z, n_test, n_slots);
}